// Round 8
// baseline (33468.039 us; speedup 1.0000x reference)
//
#include <hip/hip_runtime.h>
#include <hip/hip_bf16.h>

#define BB   64
#define TENC 1024
#define DENC 256
#define HN   256
#define AN   128
#define NFC  10
#define EMBD 64
#define VN   96
#define TT   255
#define AGT  __HIP_MEMORY_SCOPE_AGENT

typedef unsigned short u16;

__device__ __forceinline__ float fsig(float x){ return 1.0f/(1.0f+__expf(-x)); }
__device__ __forceinline__ float ftanh(float x){ return 1.0f - 2.0f/(1.0f+__expf(2.0f*x)); }
__device__ __forceinline__ float b2f(u16 v){ return __uint_as_float(((unsigned)v) << 16); }
__device__ __forceinline__ u16 f2b(float x){
    __hip_bfloat16 h = __float2bfloat16(x);
    return *reinterpret_cast<u16*>(&h);
}
__device__ __forceinline__ float4 ld_bf4(const u16* p){
    ushort4 v = *(const ushort4*)p;
    return make_float4(b2f(v.x), b2f(v.y), b2f(v.z), b2f(v.w));
}
// L2-bypassing (coherent-point) accesses for mutable cross-block state
__device__ __forceinline__ float aldf(const float* p){
    return __hip_atomic_load(p, __ATOMIC_RELAXED, AGT);
}
__device__ __forceinline__ void astf(float* p, float v){
    __hip_atomic_store(p, v, __ATOMIC_RELAXED, AGT);
}
__device__ __forceinline__ unsigned aldu(const unsigned* p){
    return __hip_atomic_load(p, __ATOMIC_RELAXED, AGT);
}

struct Params {
    const u16* encb; const u16* enc_projb; const u16* WdecTb;
    const float* conv_w; const float* W_loc; const float* v_w;
    const int* lengths; const int* targets; const float* emb;
    const float* WcombP; const float* biasw;
    const float* out_w1; const float* out_b1; const float* out_w2; const float* out_b2;
    float* e0; float* e1; float* ctxU0; float* ctxU1; float* SU0; float* SU1;
    float* h0; float* h1; float* c_st; float* hidA; float* hidB;
    unsigned* cnt_h; unsigned* cnt_c; unsigned* cnt_hid;
    float* out;
};

// ---------------- one-time prep ----------------
__global__ void k_prep(const float* __restrict__ enc,
                       const float* __restrict__ W_ih, const float* __restrict__ W_hh,
                       const float* __restrict__ b_ih, const float* __restrict__ b_hh,
                       const float* __restrict__ W_dec,
                       u16* __restrict__ encb, u16* __restrict__ WdecTb,
                       float* __restrict__ WcombP, float* __restrict__ biasw,
                       float* __restrict__ e_init, float* __restrict__ S_init,
                       unsigned* __restrict__ cnts, int n_cnts)
{
    int tid = blockIdx.x*blockDim.x + threadIdx.x;
    int tot = blockDim.x*gridDim.x;
    for (size_t i = tid; i < (size_t)BB*TENC*DENC; i += tot) encb[i] = f2b(enc[i]);
    // WcombP[k][rowP], rowP = ug*16 + gidx*4 + ul  <->  g = gidx*256 + ug*4 + ul
    for (int i = tid; i < 576*1024; i += tot){
        int k = i >> 10, rp = i & 1023;
        int ug = rp >> 4, q = rp & 15, gidx = q >> 2, ul = q & 3;
        int g = gidx*256 + ug*4 + ul;
        WcombP[i] = (k < 320) ? W_ih[(size_t)g*320 + k] : W_hh[(size_t)g*256 + (k-320)];
    }
    for (int i = tid; i < 1024; i += tot) biasw[i] = b_ih[i] + b_hh[i];
    for (int i = tid; i < 256*128; i += tot){ int u = i>>7, a = i&127; WdecTb[i] = f2b(W_dec[a*256 + u]); }
    for (int i = tid; i < BB*TENC; i += tot) e_init[i] = 1.0f;
    for (int i = tid; i < BB; i += tot) S_init[i] = (float)TENC;
    for (int i = tid; i < n_cnts; i += tot) cnts[i] = 0u;
}

// ---------------- one-time: enc_projb[b,t,a] (bf16) ----------------
__global__ __launch_bounds__(128) void k_encproj(const float* __restrict__ enc,
                                                 const float* __restrict__ W_enc,
                                                 u16* __restrict__ enc_projb)
{
    __shared__ float rows[32][256];
    int r0 = blockIdx.x * 32;
    for (int i = threadIdx.x; i < 32*256; i += 128)
        rows[i>>8][i&255] = enc[(size_t)r0*256 + i];
    __syncthreads();
    int a = threadIdx.x;
    float acc[32];
    #pragma unroll
    for (int r=0;r<32;r++) acc[r]=0.f;
    const float* w = W_enc + a*256;
    for (int d=0; d<256; d+=4){
        float4 wv = *(const float4*)(w + d);
        #pragma unroll
        for (int r=0;r<32;r++){
            float4 rv = *(const float4*)(&rows[r][d]);
            acc[r] += wv.x*rv.x + wv.y*rv.y + wv.z*rv.z + wv.w*rv.w;
        }
    }
    for (int r=0;r<32;r++) enc_projb[(size_t)(r0+r)*AN + a] = f2b(acc[r]);
}

// ---------------- LDS union ----------------
union alignas(16) SMemU {
    struct { float xh[8][584]; float invS[8]; float part[4][16][9]; float gates[8][17]; } gat;
    struct { float hdec[128]; float hbuf[256]; float part[256]; float ehalo[68]; float cw[52];
             float loc[64][11]; float wlocT[10*128]; float evals[64];
             float ep[64][33]; float wacc[4][256]; } att;
    struct { float xh[512]; float part[32][9]; } hid2;
    struct { float hs[256]; float part[12][17]; } lg2;
};

// ---------------- sync primitives (no cache-maintenance) ----------------
__device__ __forceinline__ void wait_ge(const unsigned* cnt, unsigned target, int tid)
{
    if (tid == 0){
        int guard = 0;
        while (aldu(cnt) < target){
            if (++guard > (1<<24)) break;   // safety valve: wrong answer beats a hang
        }
        __atomic_signal_fence(__ATOMIC_ACQUIRE);
    }
    __syncthreads();
}
__device__ __forceinline__ void arrive(unsigned* cnt, int tid)
{
    __syncthreads();                         // compiler drains vmcnt before s_barrier
    if (tid == 0){
        __atomic_signal_fence(__ATOMIC_RELEASE);
        __hip_atomic_fetch_add(cnt, 1u, __ATOMIC_RELAXED, AGT);
    }
}

// ---------------- phases (shared by persistent and fallback paths) ----------------
// block roles: X = (j&7)*8 + ((j>>3)&7)  (batch / gates-ug), Q = j>>6 (chunk-pair / gates-bg)
__device__ __forceinline__ void gates_phase(const Params& P, int t, int X, int Q, int tid, SMemU& u)
{
    const int wr = t & 1;
    const float* ctxU_r = wr ? P.ctxU0 : P.ctxU1;
    float*       ctxU_w = wr ? P.ctxU1 : P.ctxU0;
    const float* SU_r   = wr ? P.SU0   : P.SU1;
    float*       SU_w   = wr ? P.SU1   : P.SU0;
    const float* h_old  = wr ? P.h0    : P.h1;
    float*       h_new  = wr ? P.h1    : P.h0;
    const int b0 = Q*8;

    if (X == 1){   // zero next-step accumulators for this batch group
        for (int i = tid; i < 8*DENC; i += 256) astf(ctxU_w + b0*DENC + i, 0.f);
        if (tid < 8) astf(SU_w + b0 + tid, 0.f);
    }
    if (tid < 8) u.gat.invS[tid] = (t == 0) ? 0.f : 1.0f / aldf(SU_r + b0 + tid);
    for (int i = tid; i < 8*EMBD; i += 256){
        int bl = i>>6, jj = i&63;
        int tok = P.targets[(b0+bl)*256 + t];
        u.gat.xh[bl][jj] = P.emb[tok*EMBD + jj];
    }
    for (int i = tid; i < 8*HN; i += 256){
        int bl = i>>8, d = i&255;
        u.gat.xh[bl][320+d] = (t == 0) ? 0.f : aldf(h_old + (b0+bl)*HN + d);
    }
    __syncthreads();
    for (int i = tid; i < 8*DENC; i += 256){
        int bl = i>>8, d = i&255;
        u.gat.xh[bl][64+d] = (t == 0) ? 0.f
            : aldf(ctxU_r + (b0+bl)*DENC + d) * u.gat.invS[bl];
    }
    __syncthreads();
    {
        const int kq = tid >> 6, lane = tid & 63, rl = lane & 15, blq = lane >> 4;
        const int rowP = X*16 + rl, bl0 = blq*2;
        const float* wp  = P.WcombP + (size_t)(kq*144)*1024 + rowP;
        const float* x0p = &u.gat.xh[bl0][kq*144];
        const float* x1p = &u.gat.xh[bl0+1][kq*144];
        float s0 = 0.f, s1 = 0.f;
        for (int k = 0; k < 144; k += 4){
            float w0 = wp[0], w1 = wp[1024], w2 = wp[2048], w3 = wp[3072]; wp += 4096;
            float4 xa = *(const float4*)(x0p + k);
            float4 xb = *(const float4*)(x1p + k);
            s0 += w0*xa.x + w1*xa.y + w2*xa.z + w3*xa.w;
            s1 += w0*xb.x + w1*xb.y + w2*xb.z + w3*xb.w;
        }
        u.gat.part[kq][rl][bl0] = s0; u.gat.part[kq][rl][bl0+1] = s1;
    }
    __syncthreads();
    if (tid < 128){
        int bl = tid >> 4, rl = tid & 15;
        float s = u.gat.part[0][rl][bl] + u.gat.part[1][rl][bl]
                + u.gat.part[2][rl][bl] + u.gat.part[3][rl][bl];
        int gidx = rl >> 2, ul = rl & 3;
        u.gat.gates[bl][rl] = s + P.biasw[gidx*256 + X*4 + ul];
    }
    __syncthreads();
    if (tid < 32){
        int bl = tid >> 2, ul = tid & 3;
        int bgl = b0 + bl, unit = X*4 + ul;
        float gi = u.gat.gates[bl][0+ul],  gf = u.gat.gates[bl][4+ul];
        float gg = u.gat.gates[bl][8+ul],  go = u.gat.gates[bl][12+ul];
        float cold = (t == 0) ? 0.f : P.c_st[bgl*HN + unit];
        float cn = fsig(gf)*cold + fsig(gi)*ftanh(gg);
        P.c_st[bgl*HN + unit] = cn;                    // block-local: normal store
        astf(h_new + bgl*HN + unit, fsig(go)*ftanh(cn));
    }
}

__device__ __forceinline__ void hid_phase(const Params& P, int t, int X, int Q, int tid, SMemU& u)
{
    // computes hid(t-1) rows [Q*32, Q*32+32) for batch X
    const int wr = t & 1;
    const float* ctxU_r = wr ? P.ctxU0 : P.ctxU1;
    const float* SU_r   = wr ? P.SU0   : P.SU1;
    const float* h_old  = wr ? P.h0    : P.h1;
    float*       hid_nw = wr ? P.hidB  : P.hidA;
    const int r0 = Q*32;
    const float invS = 1.0f / aldf(SU_r + X);
    u.hid2.xh[tid]       = aldf(h_old + X*HN + tid);
    u.hid2.xh[256 + tid] = aldf(ctxU_r + X*DENC + tid) * invS;
    __syncthreads();
    {
        const int rl = tid & 31, kh = tid >> 5;
        const float* w1 = P.out_w1 + (size_t)(r0+rl)*512 + kh*64;
        const float* xp = &u.hid2.xh[kh*64];
        float a0=0.f,a1=0.f,a2=0.f,a3=0.f;
        for (int k = 0; k < 64; k += 4){
            float4 wv = *(const float4*)(w1 + k);
            float4 xv = *(const float4*)(xp + k);
            a0 += wv.x*xv.x; a1 += wv.y*xv.y; a2 += wv.z*xv.z; a3 += wv.w*xv.w;
        }
        u.hid2.part[rl][kh] = (a0+a1)+(a2+a3);
    }
    __syncthreads();
    if (tid < 32){
        int r = r0 + tid;
        float s = 0.f;
        #pragma unroll
        for (int kh = 0; kh < 8; kh++) s += u.hid2.part[tid][kh];
        astf(hid_nw + X*HN + r, ftanh(s + P.out_b1[r]));
    }
}

__device__ __forceinline__ void att_phase(const Params& P, int t, int X, int Q, int tid, SMemU& u)
{
    const int wr = t & 1;
    float*       ctxU_w = wr ? P.ctxU1 : P.ctxU0;
    const float* SU_r   = wr ? P.SU0   : P.SU1;
    float*       SU_w   = wr ? P.SU1   : P.SU0;
    const float* h_new  = wr ? P.h1    : P.h0;
    const float* e_prev = wr ? P.e0    : P.e1;
    float*       e_new  = wr ? P.e1    : P.e0;

    const int b = X;
    const int len = P.lengths[b];
    const float invS = 1.0f / aldf(SU_r + b);

    if (tid < 50) u.att.cw[tid] = P.conv_w[tid];
    for (int i = tid; i < 1280; i += 256){
        int f = i >> 7, a = i & 127;
        u.att.wlocT[f*128 + a] = P.W_loc[a*NFC + f];
    }
    u.att.hbuf[tid] = aldf(h_new + b*HN + tid);
    __syncthreads();
    {   // hdec partials from LDS hbuf
        int a = tid & 127, half = tid >> 7;
        const u16* wd = P.WdecTb + (size_t)(half*128)*AN + a;
        const float* hb = &u.att.hbuf[half*128];
        float s0 = 0.f, s1 = 0.f;
        #pragma unroll 4
        for (int uu = 0; uu < 128; uu += 2){
            s0 += hb[uu]   * b2f(wd[(size_t)uu*AN]);
            s1 += hb[uu+1] * b2f(wd[(size_t)(uu+1)*AN]);
        }
        u.att.part[tid] = s0 + s1;
    }
    __syncthreads();
    if (tid < 128) u.att.hdec[tid] = u.att.part[tid] + u.att.part[tid+128];
    __syncthreads();

    float cax=0.f, cay=0.f, caz=0.f, caw=0.f;   // ctx acc across both chunks
    float se_sum = 0.f;
    for (int kk = 0; kk < 2; kk++){
        const int ch = Q + 8*kk;
        const int t0 = ch*64;
        float* e_row = e_new + b*TENC + t0;
        int nv = len - t0; nv = nv < 0 ? 0 : (nv > 64 ? 64 : nv);
        if (nv == 0){
            if (tid < 64) astf(e_row + tid, 0.f);
            continue;
        }
        __syncthreads();
        if (tid < 68){
            int g = t0 - 2 + tid;
            u.att.ehalo[tid] = (g >= 0 && g < TENC) ? aldf(e_prev + b*TENC + g) : 0.f;
        }
        __syncthreads();
        if (tid < 64){
            #pragma unroll
            for (int f = 0; f < NFC; f++){
                float s = 0.f;
                #pragma unroll
                for (int k2 = 0; k2 < 5; k2++) s += u.att.ehalo[tid+k2] * u.att.cw[f*5+k2];
                u.att.loc[tid][f] = s * invS;
            }
        }
        __syncthreads();
        {   // energy partials: thread = (ag 32) x (pg 8)
            const int ag = tid & 31, pg = tid >> 5;
            const int a0 = ag*4;
            float4 hd4 = *(const float4*)&u.att.hdec[a0];
            float4 vv  = *(const float4*)(P.v_w + a0);
            const u16* epr = P.enc_projb + ((size_t)(b*TENC + t0))*AN + a0;
            #pragma unroll
            for (int i = 0; i < 8; i++){
                int p = pg*8 + i;
                if (p < nv){
                    float4 er = ld_bf4(epr + (size_t)p*AN);
                    float x0 = er.x + hd4.x, x1 = er.y + hd4.y;
                    float x2 = er.z + hd4.z, x3 = er.w + hd4.w;
                    #pragma unroll
                    for (int f = 0; f < NFC; f++){
                        float lf = u.att.loc[p][f];
                        const float* wla = &u.att.wlocT[f*128 + a0];
                        x0 += lf*wla[0]; x1 += lf*wla[1]; x2 += lf*wla[2]; x3 += lf*wla[3];
                    }
                    u.att.ep[p][ag] = vv.x*ftanh(x0) + vv.y*ftanh(x1)
                                    + vv.z*ftanh(x2) + vv.w*ftanh(x3);
                }
            }
        }
        __syncthreads();
        if (tid < 64){
            int p = tid;
            float e = 0.f;
            if (p < nv){
                float s0 = 0.f, s1 = 0.f;
                #pragma unroll
                for (int j2 = 0; j2 < 32; j2 += 2){ s0 += u.att.ep[p][j2]; s1 += u.att.ep[p][j2+1]; }
                e = __expf(s0 + s1);   // |energy| <= sum|v| ~ 5.2
            }
            u.att.evals[p] = e;
            astf(e_row + p, e);
            float se = e;
            #pragma unroll
            for (int off = 32; off; off >>= 1) se += __shfl_xor(se, off);
            if (tid == 0) se_sum += se;
        }
        __syncthreads();
        {   // ctx partial, accumulate in registers across chunks
            const int dq = tid & 63, pq = tid >> 6;
            const u16* encb = P.encb + ((size_t)(b*TENC + t0))*DENC + dq*4;
            for (int i = 0; i < 16; i++){
                int p = pq + i*4;
                if (p < nv){
                    float ev = u.att.evals[p];
                    float4 ex = ld_bf4(encb + (size_t)p*DENC);
                    cax += ev*ex.x; cay += ev*ex.y; caz += ev*ex.z; caw += ev*ex.w;
                }
            }
        }
        __syncthreads();
    }
    {
        const int dq = tid & 63, pq = tid >> 6;
        float4 r; r.x=cax; r.y=cay; r.z=caz; r.w=caw;
        *(float4*)&u.att.wacc[pq][dq*4] = r;
    }
    __syncthreads();
    {
        float s = u.att.wacc[0][tid] + u.att.wacc[1][tid]
                + u.att.wacc[2][tid] + u.att.wacc[3][tid];
        __hip_atomic_fetch_add(ctxU_w + b*DENC + tid, s, __ATOMIC_RELAXED, AGT);
    }
    if (tid == 0)
        __hip_atomic_fetch_add(SU_w + b, se_sum, __ATOMIC_RELAXED, AGT);
}

__device__ __forceinline__ void logits_phase(const Params& P, int t, int X, int Q, int tid, SMemU& u)
{
    const int wr = t & 1;
    const float* hid_pv = wr ? P.hidA : P.hidB;
    const int v0 = Q*12;
    u.lg2.hs[tid] = aldf(hid_pv + X*HN + tid);
    __syncthreads();
    {
        const int vl = tid & 15, kq = tid >> 4;
        if (vl < 12){
            const float* w2 = P.out_w2 + (size_t)(v0+vl)*HN + kq*16;
            const float* xp = &u.lg2.hs[kq*16];
            float a0=0.f,a1=0.f,a2=0.f,a3=0.f;
            for (int k = 0; k < 16; k += 4){
                float4 wv = *(const float4*)(w2 + k);
                float4 xv = *(const float4*)(xp + k);
                a0 += wv.x*xv.x; a1 += wv.y*xv.y; a2 += wv.z*xv.z; a3 += wv.w*xv.w;
            }
            u.lg2.part[vl][kq] = (a0+a1)+(a2+a3);
        }
    }
    __syncthreads();
    if (tid < 12){
        int v = v0 + tid;
        float s = 0.f;
        #pragma unroll
        for (int kq2 = 0; kq2 < 16; kq2++) s += u.lg2.part[tid][kq2];
        P.out[((size_t)X*TT + (t-2))*VN + v] = s + P.out_b2[v];
    }
}

// ---------------- persistent loop (coop-launched for co-residency; NO grid.sync) ----------------
__global__ __launch_bounds__(256, 2) void k_loop(Params P)
{
    __shared__ SMemU u;
    const int j = blockIdx.x, tid = threadIdx.x;
    const int X = (j & 7)*8 + ((j >> 3) & 7);   // batch role (pinned to XCD j&7)
    const int Q = j >> 6;                        // chunk-pair / gates batch-group
    const int g = X >> 3;                        // batch-group of this block's batch role

    for (int t = 0; t <= 256; t++){
        if (t <= 254){
            if (t >= 1) wait_ge(P.cnt_c + (t-1)*8 + Q, 64, tid);
            gates_phase(P, t, X, Q, tid, u);
            arrive(P.cnt_h + t*8 + Q, tid);
        }
        if (t <= 254)      wait_ge(P.cnt_h + t*8 + g, 64, tid);
        else if (t == 255) wait_ge(P.cnt_c + 254*8 + g, 64, tid);
        if (t >= 1 && t <= 255){
            hid_phase(P, t, X, Q, tid, u);
            arrive(P.cnt_hid + t*64 + X, tid);
        }
        if (t <= 254){
            att_phase(P, t, X, Q, tid, u);
            arrive(P.cnt_c + t*8 + g, tid);
        }
        if (t >= 2){
            wait_ge(P.cnt_hid + (t-1)*64 + X, 8, tid);
            logits_phase(P, t, X, Q, tid, u);
        }
    }
}

// ---------------- per-step fallback (proven ~12 ms path) ----------------
__global__ __launch_bounds__(256) void k_cell_step(Params P, int t)
{
    __shared__ SMemU u;
    const int j = blockIdx.x;
    const int X = (j & 7)*8 + ((j >> 3) & 7);
    const int Q = j >> 6;
    gates_phase(P, t, X, Q, threadIdx.x, u);
}
__global__ __launch_bounds__(256) void k_att_step(Params P, int t)
{
    __shared__ SMemU u;
    const int j = blockIdx.x, tid = threadIdx.x;
    const int X = (j & 7)*8 + ((j >> 3) & 7);
    const int Q = j >> 6;
    if (t >= 1 && t <= 255){ hid_phase(P, t, X, Q, tid, u); __syncthreads(); }
    if (t <= 254){ att_phase(P, t, X, Q, tid, u); __syncthreads(); }
    if (t >= 2) logits_phase(P, t, X, Q, tid, u);
}

extern "C" void kernel_launch(void* const* d_in, const int* in_sizes, int n_in,
                              void* d_out, int out_size, void* d_ws, size_t ws_size,
                              hipStream_t stream)
{
    const float* enc     = (const float*)d_in[0];
    const int*   lengths = (const int*)  d_in[1];
    const int*   targets = (const int*)  d_in[2];
    const float* emb     = (const float*)d_in[3];
    const float* W_ih    = (const float*)d_in[4];
    const float* W_hh    = (const float*)d_in[5];
    const float* b_ih    = (const float*)d_in[6];
    const float* b_hh    = (const float*)d_in[7];
    const float* conv_w  = (const float*)d_in[8];
    const float* W_enc   = (const float*)d_in[9];
    const float* W_dec   = (const float*)d_in[10];
    const float* W_loc   = (const float*)d_in[11];
    const float* v_w     = (const float*)d_in[12];
    const float* out_w1  = (const float*)d_in[13];
    const float* out_b1  = (const float*)d_in[14];
    const float* out_w2  = (const float*)d_in[15];
    const float* out_b2  = (const float*)d_in[16];
    float* out = (float*)d_out;

    float* ws = (float*)d_ws;
    size_t off = 0;
    auto alloc = [&](size_t n){ float* p = ws + off; off += n; return p; };
    u16*   encb      = (u16*)  alloc((size_t)BB*TENC*DENC/2);
    u16*   enc_projb = (u16*)  alloc((size_t)BB*TENC*AN/2);
    u16*   WdecTb    = (u16*)  alloc(256*128/2);
    float* WcombP    = alloc(576*1024);
    float* biasw     = alloc(1024);
    float* e0        = alloc(BB*TENC);
    float* e1        = alloc(BB*TENC);
    float* ctxU0     = alloc(BB*DENC);
    float* ctxU1     = alloc(BB*DENC);
    float* SU0       = alloc(BB);
    float* SU1       = alloc(BB);
    float* h0        = alloc(BB*HN);
    float* h1        = alloc(BB*HN);
    float* c_st      = alloc(BB*HN);
    float* hidA      = alloc(BB*HN);
    float* hidB      = alloc(BB*HN);
    const int N_CNT = 258*8 + 258*8 + 258*64;
    unsigned* cnts   = (unsigned*)alloc(N_CNT);
    if (off * sizeof(float) > ws_size) return;   // visible failure if ws too small

    k_prep<<<dim3(512), dim3(256), 0, stream>>>(enc, W_ih, W_hh, b_ih, b_hh, W_dec,
                                                encb, WdecTb, WcombP, biasw,
                                                e1, SU1, cnts, N_CNT);
    k_encproj<<<dim3(2048), dim3(128), 0, stream>>>(enc, W_enc, enc_projb);

    Params pr;
    pr.encb = encb; pr.enc_projb = enc_projb; pr.WdecTb = WdecTb;
    pr.conv_w = conv_w; pr.W_loc = W_loc; pr.v_w = v_w;
    pr.lengths = lengths; pr.targets = targets; pr.emb = emb;
    pr.WcombP = WcombP; pr.biasw = biasw;
    pr.out_w1 = out_w1; pr.out_b1 = out_b1; pr.out_w2 = out_w2; pr.out_b2 = out_b2;
    pr.e0 = e0; pr.e1 = e1; pr.ctxU0 = ctxU0; pr.ctxU1 = ctxU1;
    pr.SU0 = SU0; pr.SU1 = SU1; pr.h0 = h0; pr.h1 = h1;
    pr.c_st = c_st; pr.hidA = hidA; pr.hidB = hidB;
    pr.cnt_h = cnts; pr.cnt_c = cnts + 258*8; pr.cnt_hid = cnts + 258*16;
    pr.out = out;

    void* args[] = { (void*)&pr };
    hipError_t err = hipLaunchCooperativeKernel((const void*)k_loop, dim3(512), dim3(256),
                                                args, 0, stream);
    if (err != hipSuccess){
        // deterministic fallback: per-step launches of the same phase code
        for (int t = 0; t <= 256; t++){
            if (t <= 254)
                k_cell_step<<<dim3(512), dim3(256), 0, stream>>>(pr, t);
            k_att_step<<<dim3(512), dim3(256), 0, stream>>>(pr, t);
        }
    }
}

// Round 9
// 18004.453 us; speedup vs baseline: 1.8589x; 1.8589x over previous
//
#include <hip/hip_runtime.h>
#include <hip/hip_bf16.h>

#define BB   64
#define TENC 1024
#define DENC 256
#define HN   256
#define AN   128
#define NFC  10
#define EMBD 64
#define VN   96
#define TT   255
#define AGT  __HIP_MEMORY_SCOPE_AGENT

typedef unsigned short u16;

__device__ __forceinline__ float fsig(float x){ return 1.0f/(1.0f+__expf(-x)); }
__device__ __forceinline__ float ftanh(float x){ return 1.0f - 2.0f/(1.0f+__expf(2.0f*x)); }
__device__ __forceinline__ float b2f(u16 v){ return __uint_as_float(((unsigned)v) << 16); }
__device__ __forceinline__ u16 f2b(float x){
    __hip_bfloat16 h = __float2bfloat16(x);
    return *reinterpret_cast<u16*>(&h);
}
__device__ __forceinline__ float4 ld_bf4(const u16* p){
    ushort4 v = *(const ushort4*)p;
    return make_float4(b2f(v.x), b2f(v.y), b2f(v.z), b2f(v.w));
}
// L3-point (L2-bypassing) accesses — used EXCLUSIVELY for ctxU/SU/cnt
__device__ __forceinline__ float aldf(const float* p){
    return __hip_atomic_load(p, __ATOMIC_RELAXED, AGT);
}
__device__ __forceinline__ void astf(float* p, float v){
    __hip_atomic_store(p, v, __ATOMIC_RELAXED, AGT);
}
__device__ __forceinline__ unsigned aldu(const unsigned* p){
    return __hip_atomic_load(p, __ATOMIC_RELAXED, AGT);
}

struct Params {
    const u16* encb; const u16* enc_projb; const u16* WdecTb;
    const float* conv_w; const float* W_loc; const float* v_w;
    const int* lengths; const int* targets; const float* emb;
    const float* WcombP; const float* biasw;
    const float* W1T; const float* out_b1; const float* W2T; const float* out_b2;
    float* e0; float* e1;
    float* ctxU[3]; float* SU[3];
    float* h0; float* h1; float* c_st; float* hidA; float* hidB;
    unsigned* cnt;
    float* out;
};

// ---------------- one-time prep ----------------
__global__ void k_prep(Params P, const float* __restrict__ enc,
                       const float* __restrict__ W_ih, const float* __restrict__ W_hh,
                       const float* __restrict__ b_ih, const float* __restrict__ b_hh,
                       const float* __restrict__ W_dec, const float* __restrict__ out_w1,
                       const float* __restrict__ out_w2)
{
    int tid = blockIdx.x*blockDim.x + threadIdx.x;
    int tot = blockDim.x*gridDim.x;
    u16* encb = (u16*)P.encb;  u16* WdecTb = (u16*)P.WdecTb;
    float* WcombP = (float*)P.WcombP; float* biasw = (float*)P.biasw;
    float* W1T = (float*)P.W1T; float* W2T = (float*)P.W2T;
    for (size_t i = tid; i < (size_t)BB*TENC*DENC; i += tot) encb[i] = f2b(enc[i]);
    // WcombP[k][rowP], rowP = ug*16 + gidx*4 + ul  <->  g = gidx*256 + ug*4 + ul
    for (int i = tid; i < 576*1024; i += tot){
        int k = i >> 10, rp = i & 1023;
        int ug = rp >> 4, q = rp & 15, gidx = q >> 2, ul = q & 3;
        int g = gidx*256 + ug*4 + ul;
        WcombP[i] = (k < 320) ? W_ih[(size_t)g*320 + k] : W_hh[(size_t)g*256 + (k-320)];
    }
    for (int i = tid; i < 1024; i += tot) biasw[i] = b_ih[i] + b_hh[i];
    for (int i = tid; i < 256*128; i += tot){ int u = i>>7, a = i&127; WdecTb[i] = f2b(W_dec[a*256 + u]); }
    for (int i = tid; i < 512*256; i += tot){ int k = i>>8, r = i&255; W1T[i] = out_w1[(size_t)r*512 + k]; }
    for (int i = tid; i < 256*96;  i += tot){ int k = i/96, v = i - k*96; W2T[i] = out_w2[(size_t)v*256 + k]; }
    for (int i = tid; i < BB*TENC; i += tot) P.e1[i] = 1.0f;
    for (int i = tid; i < BB*DENC; i += tot){
        P.ctxU[0][i] = 0.f; P.ctxU[1][i] = 0.f; P.ctxU[2][i] = 0.f;
    }
    for (int i = tid; i < BB; i += tot){
        P.SU[0][i] = 0.f; P.SU[1][i] = 0.f; P.SU[2][i] = (float)TENC;
    }
    for (int i = tid; i < 256*8; i += tot) P.cnt[i] = 0u;
}

// ---------------- one-time: enc_projb[b,t,a] (bf16) ----------------
__global__ __launch_bounds__(128) void k_encproj(const float* __restrict__ enc,
                                                 const float* __restrict__ W_enc,
                                                 u16* __restrict__ enc_projb)
{
    __shared__ float rows[32][256];
    int r0 = blockIdx.x * 32;
    for (int i = threadIdx.x; i < 32*256; i += 128)
        rows[i>>8][i&255] = enc[(size_t)r0*256 + i];
    __syncthreads();
    int a = threadIdx.x;
    float acc[32];
    #pragma unroll
    for (int r=0;r<32;r++) acc[r]=0.f;
    const float* w = W_enc + a*256;
    for (int d=0; d<256; d+=4){
        float4 wv = *(const float4*)(w + d);
        #pragma unroll
        for (int r=0;r<32;r++){
            float4 rv = *(const float4*)(&rows[r][d]);
            acc[r] += wv.x*rv.x + wv.y*rv.y + wv.z*rv.z + wv.w*rv.w;
        }
    }
    for (int r=0;r<32;r++) enc_projb[(size_t)(r0+r)*AN + a] = f2b(acc[r]);
}

// ---------------- LDS union ----------------
union alignas(16) SMemU {
    struct { float hdec[128]; float hbuf[256]; float part[256]; float ehalo[68]; float cw[52];
             float loc[64][11]; float wlocT[10*128]; float evals[64];
             float ep[64][33]; float wacc[4][256]; } att;
    struct { float xh[8][584]; float invS[8]; float part[4][16][9]; float gates[8][17]; } gat;
    struct { float xh[512]; } hid2;
    struct { float hs[256]; } lg2;
};

// ---------------- sync primitives ----------------
__device__ __forceinline__ void wait_ge(const unsigned* cnt, unsigned target, int tid)
{
    if (tid == 0){
        int guard = 0;
        while (aldu(cnt) < target){
            if (++guard > (1<<24)) break;   // safety valve: wrong answer beats a hang
        }
        __atomic_signal_fence(__ATOMIC_ACQUIRE);
    }
    __syncthreads();
}
__device__ __forceinline__ void arrive(unsigned* cnt, int tid)
{
    __syncthreads();                         // drains vmcnt (incl. atomics) before s_barrier
    if (tid == 0){
        __atomic_signal_fence(__ATOMIC_RELEASE);
        __hip_atomic_fetch_add(cnt, 1u, __ATOMIC_RELAXED, AGT);
    }
}

// ---------------- ATT(t): blocks 0..511, b = blk>>3, chunks (blk&7), (blk&7)+8 ----------------
__device__ __forceinline__ void att_role(const Params& P, int t, int blk, int tid, SMemU& u)
{
    const float* e_prev = (t & 1) ? P.e0 : P.e1;
    float*       e_new  = (t & 1) ? P.e1 : P.e0;
    const float* hcur   = (t & 1) ? P.h1 : P.h0;      // h(t), written previous dispatch
    float*       ctxU_w = P.ctxU[t % 3];
    float*       SU_w   = P.SU[t % 3];
    const float* SU_r   = P.SU[(t + 2) % 3];

    const int b = blk >> 3;
    const int q = blk & 7;
    const int len = P.lengths[b];
    const float invS = 1.0f / aldf(SU_r + b);

    if (q == 7){   // zero next step's accumulators (buffer untouched by anyone this dispatch)
        float* zc = P.ctxU[(t + 1) % 3];
        for (int i = tid; i < DENC; i += 256) astf(zc + b*DENC + i, 0.f);
        if (tid == 0) astf(P.SU[(t + 1) % 3] + b, 0.f);
    }

    if (tid < 50) u.att.cw[tid] = P.conv_w[tid];
    for (int i = tid; i < 1280; i += 256){
        int f = i >> 7, a = i & 127;
        u.att.wlocT[f*128 + a] = P.W_loc[a*NFC + f];
    }
    u.att.hbuf[tid] = hcur[b*HN + tid];
    __syncthreads();
    {   // hdec partials: thread (a, half)
        int a = tid & 127, half = tid >> 7;
        const u16* wd = P.WdecTb + (size_t)(half*128)*AN + a;
        const float* hb = &u.att.hbuf[half*128];
        float s0 = 0.f, s1 = 0.f;
        #pragma unroll 4
        for (int uu = 0; uu < 128; uu += 2){
            s0 += hb[uu]   * b2f(wd[(size_t)uu*AN]);
            s1 += hb[uu+1] * b2f(wd[(size_t)(uu+1)*AN]);
        }
        u.att.part[tid] = s0 + s1;
    }
    __syncthreads();
    if (tid < 128) u.att.hdec[tid] = u.att.part[tid] + u.att.part[tid+128];
    __syncthreads();

    float cax=0.f, cay=0.f, caz=0.f, caw=0.f;
    float se_sum = 0.f;
    for (int kk = 0; kk < 2; kk++){
        const int ch = q + 8*kk;
        const int t0 = ch*64;
        float* e_row = e_new + b*TENC + t0;
        int nv = len - t0; nv = nv < 0 ? 0 : (nv > 64 ? 64 : nv);
        if (nv == 0){
            if (tid < 64) e_row[tid] = 0.f;
            continue;
        }
        __syncthreads();
        if (tid < 68){
            int g = t0 - 2 + tid;
            u.att.ehalo[tid] = (g >= 0 && g < TENC) ? e_prev[b*TENC + g] : 0.f;
        }
        __syncthreads();
        if (tid < 64){
            #pragma unroll
            for (int f = 0; f < NFC; f++){
                float s = 0.f;
                #pragma unroll
                for (int k2 = 0; k2 < 5; k2++) s += u.att.ehalo[tid+k2] * u.att.cw[f*5+k2];
                u.att.loc[tid][f] = s * invS;
            }
        }
        __syncthreads();
        {   // energy partials: thread = (ag 32) x (pg 8)
            const int ag = tid & 31, pg = tid >> 5;
            const int a0 = ag*4;
            float4 hd4 = *(const float4*)&u.att.hdec[a0];
            float4 vv  = *(const float4*)(P.v_w + a0);
            const u16* epr = P.enc_projb + ((size_t)(b*TENC + t0))*AN + a0;
            #pragma unroll
            for (int i = 0; i < 8; i++){
                int p = pg*8 + i;
                if (p < nv){
                    float4 er = ld_bf4(epr + (size_t)p*AN);
                    float x0 = er.x + hd4.x, x1 = er.y + hd4.y;
                    float x2 = er.z + hd4.z, x3 = er.w + hd4.w;
                    #pragma unroll
                    for (int f = 0; f < NFC; f++){
                        float lf = u.att.loc[p][f];
                        const float* wla = &u.att.wlocT[f*128 + a0];
                        x0 += lf*wla[0]; x1 += lf*wla[1]; x2 += lf*wla[2]; x3 += lf*wla[3];
                    }
                    u.att.ep[p][ag] = vv.x*ftanh(x0) + vv.y*ftanh(x1)
                                    + vv.z*ftanh(x2) + vv.w*ftanh(x3);
                }
            }
        }
        __syncthreads();
        if (tid < 64){
            int p = tid;
            float e = 0.f;
            if (p < nv){
                float s0 = 0.f, s1 = 0.f;
                #pragma unroll
                for (int j2 = 0; j2 < 32; j2 += 2){ s0 += u.att.ep[p][j2]; s1 += u.att.ep[p][j2+1]; }
                e = __expf(s0 + s1);   // |energy| <= sum|v| ~ 5.2
            }
            u.att.evals[p] = e;
            e_row[p] = e;
            float se = e;
            #pragma unroll
            for (int off = 32; off; off >>= 1) se += __shfl_xor(se, off);
            if (tid == 0) se_sum += se;
        }
        __syncthreads();
        {   // ctx partial, accumulated in registers across chunks
            const int dq = tid & 63, pq = tid >> 6;
            const u16* encb = P.encb + ((size_t)(b*TENC + t0))*DENC + dq*4;
            for (int i = 0; i < 16; i++){
                int p = pq + i*4;
                if (p < nv){
                    float ev = u.att.evals[p];
                    float4 ex = ld_bf4(encb + (size_t)p*DENC);
                    cax += ev*ex.x; cay += ev*ex.y; caz += ev*ex.z; caw += ev*ex.w;
                }
            }
        }
        __syncthreads();
    }
    {
        const int dq = tid & 63, pq = tid >> 6;
        float4 r; r.x=cax; r.y=cay; r.z=caz; r.w=caw;
        *(float4*)&u.att.wacc[pq][dq*4] = r;
    }
    __syncthreads();
    {
        float s = u.att.wacc[0][tid] + u.att.wacc[1][tid]
                + u.att.wacc[2][tid] + u.att.wacc[3][tid];
        __hip_atomic_fetch_add(ctxU_w + b*DENC + tid, s, __ATOMIC_RELAXED, AGT);
    }
    if (tid == 0)
        __hip_atomic_fetch_add(SU_w + b, se_sum, __ATOMIC_RELAXED, AGT);
}

// ---------------- GATES(s): blocks 0..511, ug = blk&63, bg = blk>>6 ----------------
__device__ __forceinline__ void gates_role(const Params& P, int s, int ug, int bg, int tid, SMemU& u)
{
    const float* h_old = (s & 1) ? P.h0 : P.h1;
    float*       h_new = (s & 1) ? P.h1 : P.h0;
    const int b0 = bg*8;
    const int c3 = (s + 2) % 3;

    if (tid < 8) u.gat.invS[tid] = (s == 0) ? 0.f : 1.0f / aldf(P.SU[c3] + b0 + tid);
    for (int i = tid; i < 8*EMBD; i += 256){
        int bl = i>>6, jj = i&63;
        int tok = P.targets[(b0+bl)*256 + s];
        u.gat.xh[bl][jj] = P.emb[tok*EMBD + jj];
    }
    for (int i = tid; i < 8*HN; i += 256){
        int bl = i>>8, d = i&255;
        u.gat.xh[bl][320+d] = (s == 0) ? 0.f : h_old[(b0+bl)*HN + d];
    }
    __syncthreads();
    for (int i = tid; i < 8*DENC; i += 256){
        int bl = i>>8, d = i&255;
        u.gat.xh[bl][64+d] = (s == 0) ? 0.f
            : aldf(P.ctxU[c3] + (b0+bl)*DENC + d) * u.gat.invS[bl];
    }
    __syncthreads();
    {
        const int kq = tid >> 6, lane = tid & 63, rl = lane & 15, blq = lane >> 4;
        const int rowP = ug*16 + rl, bl0 = blq*2;
        const float* wp  = P.WcombP + (size_t)(kq*144)*1024 + rowP;
        const float* x0p = &u.gat.xh[bl0][kq*144];
        const float* x1p = &u.gat.xh[bl0+1][kq*144];
        float s0 = 0.f, s1 = 0.f;
        for (int k = 0; k < 144; k += 4){
            float w0 = wp[0], w1 = wp[1024], w2 = wp[2048], w3 = wp[3072]; wp += 4096;
            float4 xa = *(const float4*)(x0p + k);
            float4 xb = *(const float4*)(x1p + k);
            s0 += w0*xa.x + w1*xa.y + w2*xa.z + w3*xa.w;
            s1 += w0*xb.x + w1*xb.y + w2*xb.z + w3*xb.w;
        }
        u.gat.part[kq][rl][bl0] = s0; u.gat.part[kq][rl][bl0+1] = s1;
    }
    __syncthreads();
    if (tid < 128){
        int bl = tid >> 4, rl = tid & 15;
        float sv = u.gat.part[0][rl][bl] + u.gat.part[1][rl][bl]
                 + u.gat.part[2][rl][bl] + u.gat.part[3][rl][bl];
        int gidx = rl >> 2, ul = rl & 3;
        u.gat.gates[bl][rl] = sv + P.biasw[gidx*256 + ug*4 + ul];
    }
    __syncthreads();
    if (tid < 32){
        int bl = tid >> 2, ul = tid & 3;
        int bgl = b0 + bl, unit = ug*4 + ul;
        float gi = u.gat.gates[bl][0+ul],  gf = u.gat.gates[bl][4+ul];
        float gg = u.gat.gates[bl][8+ul],  go = u.gat.gates[bl][12+ul];
        float cold = (s == 0) ? 0.f : P.c_st[bgl*HN + unit];
        float cn = fsig(gf)*cold + fsig(gi)*ftanh(gg);
        P.c_st[bgl*HN + unit] = cn;
        h_new[bgl*HN + unit] = fsig(go)*ftanh(cn);
    }
}

// ---------------- HID(t-1) + LOGITS(t-2): blocks 512..575, one batch each ----------------
__device__ __forceinline__ void hid_role(const Params& P, int t, int bb, int tid, SMemU& u)
{
    const int wr = t & 1;
    const float* h_old  = ((t + 1) & 1) ? P.h1 : P.h0;   // h(t-1)
    float*       hid_nw = wr ? P.hidB : P.hidA;          // hid(t-1)
    const int c3 = (t + 2) % 3;                          // ctx(t-1)
    const float invS = 1.0f / aldf(P.SU[c3] + bb);
    u.hid2.xh[tid]       = h_old[bb*HN + tid];
    u.hid2.xh[256 + tid] = aldf(P.ctxU[c3] + bb*DENC + tid) * invS;
    __syncthreads();
    {
        const float* wp = P.W1T + tid;
        float a0=0.f, a1=0.f, a2=0.f, a3=0.f;
        for (int k = 0; k < 512; k += 4){
            a0 += wp[(size_t)(k+0)*256] * u.hid2.xh[k+0];
            a1 += wp[(size_t)(k+1)*256] * u.hid2.xh[k+1];
            a2 += wp[(size_t)(k+2)*256] * u.hid2.xh[k+2];
            a3 += wp[(size_t)(k+3)*256] * u.hid2.xh[k+3];
        }
        hid_nw[bb*HN + tid] = ftanh((a0+a1)+(a2+a3) + P.out_b1[tid]);
    }
}
__device__ __forceinline__ void logits_role(const Params& P, int t, int bb, int tid, SMemU& u)
{
    const int wr = t & 1;
    const float* hid_pv = wr ? P.hidA : P.hidB;          // hid(t-2)
    __syncthreads();
    u.lg2.hs[tid] = hid_pv[bb*HN + tid];
    __syncthreads();
    if (tid < VN){
        const float* wp = P.W2T + tid;
        float a0=0.f, a1=0.f, a2=0.f, a3=0.f;
        for (int k = 0; k < 256; k += 4){
            a0 += wp[(size_t)(k+0)*96] * u.lg2.hs[k+0];
            a1 += wp[(size_t)(k+1)*96] * u.lg2.hs[k+1];
            a2 += wp[(size_t)(k+2)*96] * u.lg2.hs[k+2];
            a3 += wp[(size_t)(k+3)*96] * u.lg2.hs[k+3];
        }
        P.out[((size_t)bb*TT + (t-2))*VN + tid] = (a0+a1)+(a2+a3) + P.out_b2[tid];
    }
}

// ---------------- one dispatch per step: att(t) -> wait -> gates(t+1) ----------------
__global__ __launch_bounds__(256) void k_step(Params P, int t)
{
    __shared__ SMemU u;
    const int blk = blockIdx.x, tid = threadIdx.x;
    if (blk < 512){
        if (t >= 0 && t <= 254){
            att_role(P, t, blk, tid, u);
            arrive(P.cnt + t*8 + (blk >> 6), tid);   // group = batches [bg*8, bg*8+8)
        }
        const int s = t + 1;
        if (s >= 0 && s <= 254){
            if (s >= 1) wait_ge(P.cnt + t*8 + (blk >> 6), 64, tid);
            gates_role(P, s, blk & 63, blk >> 6, tid, u);
        }
    } else {
        const int bb = blk - 512;
        if (t >= 1 && t <= 255) hid_role(P, t, bb, tid, u);
        if (t >= 2 && t <= 256) logits_role(P, t, bb, tid, u);
    }
}

extern "C" void kernel_launch(void* const* d_in, const int* in_sizes, int n_in,
                              void* d_out, int out_size, void* d_ws, size_t ws_size,
                              hipStream_t stream)
{
    const float* enc     = (const float*)d_in[0];
    const int*   lengths = (const int*)  d_in[1];
    const int*   targets = (const int*)  d_in[2];
    const float* emb     = (const float*)d_in[3];
    const float* W_ih    = (const float*)d_in[4];
    const float* W_hh    = (const float*)d_in[5];
    const float* b_ih    = (const float*)d_in[6];
    const float* b_hh    = (const float*)d_in[7];
    const float* conv_w  = (const float*)d_in[8];
    const float* W_enc   = (const float*)d_in[9];
    const float* W_dec   = (const float*)d_in[10];
    const float* W_loc   = (const float*)d_in[11];
    const float* v_w     = (const float*)d_in[12];
    const float* out_w1  = (const float*)d_in[13];
    const float* out_b1  = (const float*)d_in[14];
    const float* out_w2  = (const float*)d_in[15];
    const float* out_b2  = (const float*)d_in[16];
    float* out = (float*)d_out;

    float* ws = (float*)d_ws;
    size_t off = 0;
    auto alloc = [&](size_t n){ float* p = ws + off; off += n; return p; };
    u16*   encb      = (u16*)  alloc((size_t)BB*TENC*DENC/2);
    u16*   enc_projb = (u16*)  alloc((size_t)BB*TENC*AN/2);
    u16*   WdecTb    = (u16*)  alloc(256*128/2);
    float* WcombP    = alloc(576*1024);
    float* biasw     = alloc(1024);
    float* W1T       = alloc(512*256);
    float* W2T       = alloc(256*96);
    float* e0        = alloc(BB*TENC);
    float* e1        = alloc(BB*TENC);
    float* ctx0      = alloc(BB*DENC);
    float* ctx1      = alloc(BB*DENC);
    float* ctx2      = alloc(BB*DENC);
    float* su0       = alloc(BB);
    float* su1       = alloc(BB);
    float* su2       = alloc(BB);
    float* h0        = alloc(BB*HN);
    float* h1        = alloc(BB*HN);
    float* c_st      = alloc(BB*HN);
    float* hidA      = alloc(BB*HN);
    float* hidB      = alloc(BB*HN);
    unsigned* cnts   = (unsigned*)alloc(256*8);
    if (off * sizeof(float) > ws_size) return;   // visible failure if ws too small

    Params pr;
    pr.encb = encb; pr.enc_projb = enc_projb; pr.WdecTb = WdecTb;
    pr.conv_w = conv_w; pr.W_loc = W_loc; pr.v_w = v_w;
    pr.lengths = lengths; pr.targets = targets; pr.emb = emb;
    pr.WcombP = WcombP; pr.biasw = biasw;
    pr.W1T = W1T; pr.out_b1 = out_b1; pr.W2T = W2T; pr.out_b2 = out_b2;
    pr.e0 = e0; pr.e1 = e1;
    pr.ctxU[0] = ctx0; pr.ctxU[1] = ctx1; pr.ctxU[2] = ctx2;
    pr.SU[0] = su0; pr.SU[1] = su1; pr.SU[2] = su2;
    pr.h0 = h0; pr.h1 = h1; pr.c_st = c_st; pr.hidA = hidA; pr.hidB = hidB;
    pr.cnt = cnts; pr.out = out;

    k_prep<<<dim3(512), dim3(256), 0, stream>>>(pr, enc, W_ih, W_hh, b_ih, b_hh, W_dec,
                                                out_w1, out_w2);
    k_encproj<<<dim3(2048), dim3(128), 0, stream>>>(enc, W_enc, enc_projb);

    for (int t = -1; t <= 256; t++){
        k_step<<<dim3(576), dim3(256), 0, stream>>>(pr, t);
    }
}

// Round 10
// 12366.348 us; speedup vs baseline: 2.7064x; 1.4559x over previous
//
#include <hip/hip_runtime.h>
#include <hip/hip_bf16.h>

#define BB   64
#define TENC 1024
#define DENC 256
#define HN   256
#define AN   128
#define NFC  10
#define EMBD 64
#define VN   96
#define TT   255

typedef unsigned short u16;

__device__ __forceinline__ float fsig(float x){ return 1.0f/(1.0f+__expf(-x)); }
__device__ __forceinline__ float ftanh(float x){ return 1.0f - 2.0f/(1.0f+__expf(2.0f*x)); }
__device__ __forceinline__ float b2f(u16 v){ return __uint_as_float(((unsigned)v) << 16); }
__device__ __forceinline__ u16 f2b(float x){
    __hip_bfloat16 h = __float2bfloat16(x);
    return *reinterpret_cast<u16*>(&h);
}
__device__ __forceinline__ float4 ld_bf4(const u16* p){
    ushort4 v = *(const ushort4*)p;
    return make_float4(b2f(v.x), b2f(v.y), b2f(v.z), b2f(v.w));
}

struct Params {
    const u16* encb; const u16* enc_projb; const u16* WdecTb;
    const float* conv_w; const float* W_loc; const float* v_w;
    const int* lengths; const int* targets; const float* emb;
    const float* WcombP; const float* biasw;
    const float* W1T; const float* out_b1; const float* W2T; const float* out_b2;
    float* e0; float* e1; float* ctxU0; float* ctxU1; float* SU0; float* SU1;
    float* h0; float* h1; float* c_st; float* hidA; float* hidB;
    u16* locb;
    float* out;
};

// ---------------- one-time prep ----------------
__global__ void k_prep(Params P, const float* __restrict__ enc,
                       const float* __restrict__ W_ih, const float* __restrict__ W_hh,
                       const float* __restrict__ b_ih, const float* __restrict__ b_hh,
                       const float* __restrict__ W_dec, const float* __restrict__ out_w1,
                       const float* __restrict__ out_w2)
{
    int tid = blockIdx.x*blockDim.x + threadIdx.x;
    int tot = blockDim.x*gridDim.x;
    u16* encb = (u16*)P.encb;  u16* WdecTb = (u16*)P.WdecTb;
    float* WcombP = (float*)P.WcombP; float* biasw = (float*)P.biasw;
    float* W1T = (float*)P.W1T; float* W2T = (float*)P.W2T;
    for (size_t i = tid; i < (size_t)BB*TENC*DENC; i += tot) encb[i] = f2b(enc[i]);
    // WcombP[k][rowP], rowP = ug*16 + gidx*4 + ul  <->  g = gidx*256 + ug*4 + ul
    for (int i = tid; i < 576*1024; i += tot){
        int k = i >> 10, rp = i & 1023;
        int ug = rp >> 4, q = rp & 15, gidx = q >> 2, ul = q & 3;
        int g = gidx*256 + ug*4 + ul;
        WcombP[i] = (k < 320) ? W_ih[(size_t)g*320 + k] : W_hh[(size_t)g*256 + (k-320)];
    }
    for (int i = tid; i < 1024; i += tot) biasw[i] = b_ih[i] + b_hh[i];
    for (int i = tid; i < 256*128; i += tot){ int u = i>>7, a = i&127; WdecTb[i] = f2b(W_dec[a*256 + u]); }
    for (int i = tid; i < 512*256; i += tot){ int k = i>>8, r = i&255; W1T[i] = out_w1[(size_t)r*512 + k]; }
    for (int i = tid; i < 256*96;  i += tot){ int k = i/96, v = i - k*96; W2T[i] = out_w2[(size_t)v*256 + k]; }
    for (int i = tid; i < BB*TENC; i += tot) P.e1[i] = 1.0f;
    for (int i = tid; i < BB; i += tot) P.SU1[i] = (float)TENC;
}

// ---------------- one-time: enc_projb[b,t,a] (bf16) ----------------
__global__ __launch_bounds__(128) void k_encproj(const float* __restrict__ enc,
                                                 const float* __restrict__ W_enc,
                                                 u16* __restrict__ enc_projb)
{
    __shared__ float rows[32][256];
    int r0 = blockIdx.x * 32;
    for (int i = threadIdx.x; i < 32*256; i += 128)
        rows[i>>8][i&255] = enc[(size_t)r0*256 + i];
    __syncthreads();
    int a = threadIdx.x;
    float acc[32];
    #pragma unroll
    for (int r=0;r<32;r++) acc[r]=0.f;
    const float* w = W_enc + a*256;
    for (int d=0; d<256; d+=4){
        float4 wv = *(const float4*)(w + d);
        #pragma unroll
        for (int r=0;r<32;r++){
            float4 rv = *(const float4*)(&rows[r][d]);
            acc[r] += wv.x*rv.x + wv.y*rv.y + wv.z*rv.z + wv.w*rv.w;
        }
    }
    for (int r=0;r<32;r++) enc_projb[(size_t)(r0+r)*AN + a] = f2b(acc[r]);
}

// ---------------- LDS union ----------------
union alignas(16) SMemU {
    struct { float xh[8][584]; float part[4][16][9]; float gates[8][17]; } gat;
    struct { float hbuf[256]; float part[256]; float loc[64][11]; float evals[64];
             float ep[64][33]; float wacc[4][256]; } att;
    struct { float erow[1036]; float cw[52]; } convt;
    struct { float xh[512]; } hid2;
    struct { float hs[256]; } lg2;
};

// ---------------- k_cell: gates [0,512) + per-batch tail [512,576) ----------------
__global__ __launch_bounds__(256) void k_cell(Params P, int t)
{
    __shared__ SMemU u;
    const int blk = blockIdx.x, tid = threadIdx.x;
    const int wr = t & 1;
    const float* ctxU_r = wr ? P.ctxU0 : P.ctxU1;
    float*       ctxU_w = wr ? P.ctxU1 : P.ctxU0;
    const float* SU_r   = wr ? P.SU0   : P.SU1;
    float*       SU_w   = wr ? P.SU1   : P.SU0;
    const float* h_old  = wr ? P.h0    : P.h1;
    float*       h_new  = wr ? P.h1    : P.h0;
    const float* hid_pv = wr ? P.hidA  : P.hidB;
    float*       hid_nw = wr ? P.hidB  : P.hidA;
    const float* e_prev = wr ? P.e0    : P.e1;

    if (blk < 512){                       // -------- gates + LSTM (t <= 254) --------
        if (t > 254) return;
        const int ug = blk & 63, bg = blk >> 6;
        const int b0 = bg*8;
        if (ug == 1){   // zero accumulators that k_att(t) will add into
            for (int i = tid; i < 8*DENC; i += 256) ctxU_w[b0*DENC + i] = 0.f;
            if (tid < 8) SU_w[b0 + tid] = 0.f;
        }
        for (int i = tid; i < 8*EMBD; i += 256){
            int bl = i>>6, jj = i&63;
            int tok = P.targets[(b0+bl)*256 + t];
            u.gat.xh[bl][jj] = P.emb[tok*EMBD + jj];
        }
        for (int i = tid; i < 8*HN; i += 256){
            int bl = i>>8, d = i&255;
            u.gat.xh[bl][320+d] = (t == 0) ? 0.f : h_old[(b0+bl)*HN + d];
        }
        for (int i = tid; i < 8*DENC; i += 256){
            int bl = i>>8, d = i&255;
            u.gat.xh[bl][64+d] = (t == 0) ? 0.f
                : ctxU_r[(b0+bl)*DENC + d] * (1.0f/SU_r[b0+bl]);
        }
        __syncthreads();
        {
            const int kq = tid >> 6, lane = tid & 63, rl = lane & 15, blq = lane >> 4;
            const int rowP = ug*16 + rl, bl0 = blq*2;
            const float* wp  = P.WcombP + (size_t)(kq*144)*1024 + rowP;
            const float* x0p = &u.gat.xh[bl0][kq*144];
            const float* x1p = &u.gat.xh[bl0+1][kq*144];
            float s0 = 0.f, s1 = 0.f;
            for (int k = 0; k < 144; k += 4){
                float w0 = wp[0], w1 = wp[1024], w2 = wp[2048], w3 = wp[3072]; wp += 4096;
                float4 xa = *(const float4*)(x0p + k);
                float4 xb = *(const float4*)(x1p + k);
                s0 += w0*xa.x + w1*xa.y + w2*xa.z + w3*xa.w;
                s1 += w0*xb.x + w1*xb.y + w2*xb.z + w3*xb.w;
            }
            u.gat.part[kq][rl][bl0] = s0; u.gat.part[kq][rl][bl0+1] = s1;
        }
        __syncthreads();
        if (tid < 128){
            int bl = tid >> 4, rl = tid & 15;
            float s = u.gat.part[0][rl][bl] + u.gat.part[1][rl][bl]
                    + u.gat.part[2][rl][bl] + u.gat.part[3][rl][bl];
            int gidx = rl >> 2, ul = rl & 3;
            u.gat.gates[bl][rl] = s + P.biasw[gidx*256 + ug*4 + ul];
        }
        __syncthreads();
        if (tid < 32){
            int bl = tid >> 2, ul = tid & 3;
            int bgl = b0 + bl, unit = ug*4 + ul;
            float gi = u.gat.gates[bl][0+ul],  gf = u.gat.gates[bl][4+ul];
            float gg = u.gat.gates[bl][8+ul],  go = u.gat.gates[bl][12+ul];
            float cold = (t == 0) ? 0.f : P.c_st[bgl*HN + unit];
            float cn = fsig(gf)*cold + fsig(gi)*ftanh(gg);
            P.c_st[bgl*HN + unit] = cn;
            h_new[bgl*HN + unit] = fsig(go)*ftanh(cn);
        }
        return;
    }

    // -------- per-batch tail: conv-loc(t), hid(t-1), logits(t-2) --------
    const int bb = blk - 512;
    if (t <= 254){   // loc(t) = conv(e(t-1)) / S(t-1), bf16
        const float invS = 1.0f / SU_r[bb];
        for (int i = tid; i < 1028; i += 256){
            int g = i - 2;
            u.convt.erow[i] = (g >= 0 && g < TENC) ? e_prev[bb*TENC + g] : 0.f;
        }
        if (tid < 50) u.convt.cw[tid] = P.conv_w[tid];
        __syncthreads();
        for (int it = 0; it < 4; it++){
            int p = tid + it*256;
            u16* lp = P.locb + (size_t)(bb*TENC + p)*NFC;
            #pragma unroll
            for (int f = 0; f < NFC; f++){
                float s = 0.f;
                #pragma unroll
                for (int k2 = 0; k2 < 5; k2++) s += u.convt.erow[p+k2] * u.convt.cw[f*5+k2];
                lp[f] = f2b(s * invS);
            }
        }
    }
    if (t >= 1 && t <= 255){   // hid(t-1)
        __syncthreads();
        const float invS = 1.0f / SU_r[bb];
        u.hid2.xh[tid]       = h_old[bb*HN + tid];
        u.hid2.xh[256 + tid] = ctxU_r[bb*DENC + tid] * invS;
        __syncthreads();
        const float* wp = P.W1T + tid;
        float a0=0.f, a1=0.f, a2=0.f, a3=0.f;
        for (int k = 0; k < 512; k += 4){
            a0 += wp[(size_t)(k+0)*256] * u.hid2.xh[k+0];
            a1 += wp[(size_t)(k+1)*256] * u.hid2.xh[k+1];
            a2 += wp[(size_t)(k+2)*256] * u.hid2.xh[k+2];
            a3 += wp[(size_t)(k+3)*256] * u.hid2.xh[k+3];
        }
        hid_nw[bb*HN + tid] = ftanh((a0+a1)+(a2+a3) + P.out_b1[tid]);
    }
    if (t >= 2){               // logits(t-2)
        __syncthreads();
        u.lg2.hs[tid] = hid_pv[bb*HN + tid];
        __syncthreads();
        if (tid < VN){
            const float* wp = P.W2T + tid;
            float a0=0.f, a1=0.f, a2=0.f, a3=0.f;
            for (int k = 0; k < 256; k += 4){
                a0 += wp[(size_t)(k+0)*96] * u.lg2.hs[k+0];
                a1 += wp[(size_t)(k+1)*96] * u.lg2.hs[k+1];
                a2 += wp[(size_t)(k+2)*96] * u.lg2.hs[k+2];
                a3 += wp[(size_t)(k+3)*96] * u.lg2.hs[k+3];
            }
            P.out[((size_t)bb*TT + (t-2))*VN + tid] = (a0+a1)+(a2+a3) + P.out_b2[tid];
        }
    }
}

// ---------------- k_att: 1024 blocks, b = blk&63 (XCD-pinned), ch = blk>>6 ----------------
__global__ __launch_bounds__(256) void k_att(Params P, int t)
{
    __shared__ SMemU u;
    const int blk = blockIdx.x, tid = threadIdx.x;
    const int wr = t & 1;
    float*       ctxU_w = wr ? P.ctxU1 : P.ctxU0;
    float*       SU_w   = wr ? P.SU1   : P.SU0;
    const float* h_new  = wr ? P.h1    : P.h0;
    float*       e_new  = wr ? P.e1    : P.e0;

    const int b  = blk & 63;
    const int ch = blk >> 6;
    const int t0 = ch*64;
    float* e_row = e_new + b*TENC + t0;
    const int len = P.lengths[b];
    int nv = len - t0; nv = nv < 0 ? 0 : (nv > 64 ? 64 : nv);
    if (nv == 0){
        if (tid < 64) e_row[tid] = 0.f;
        return;
    }

    const int ag = tid & 31, pg = tid >> 5;
    const int a0 = ag*4;
    float4 vv = *(const float4*)(P.v_w + a0);
    float4 wl[NFC];
    #pragma unroll
    for (int f = 0; f < NFC; f++){
        wl[f].x = P.W_loc[(a0+0)*NFC+f]; wl[f].y = P.W_loc[(a0+1)*NFC+f];
        wl[f].z = P.W_loc[(a0+2)*NFC+f]; wl[f].w = P.W_loc[(a0+3)*NFC+f];
    }
    // ph0: stage h and precomputed loc
    u.att.hbuf[tid] = h_new[b*HN + tid];
    {
        const u16* lsrc = P.locb + (size_t)(b*TENC + t0)*NFC;
        for (int i = tid; i < 640; i += 256)
            u.att.loc[i/10][i%10] = b2f(lsrc[i]);
    }
    __syncthreads();
    // ph1: hdec partials
    {
        int a = tid & 127, half = tid >> 7;
        const u16* wd = P.WdecTb + (size_t)(half*128)*AN + a;
        const float* hb = &u.att.hbuf[half*128];
        float s0 = 0.f, s1 = 0.f;
        #pragma unroll 4
        for (int uu = 0; uu < 128; uu += 2){
            s0 += hb[uu]   * b2f(wd[(size_t)uu*AN]);
            s1 += hb[uu+1] * b2f(wd[(size_t)(uu+1)*AN]);
        }
        u.att.part[tid] = s0 + s1;
    }
    __syncthreads();
    // ph2: energy (hdec reduce folded in)
    {
        float4 hd4;
        hd4.x = u.att.part[a0+0] + u.att.part[128+a0+0];
        hd4.y = u.att.part[a0+1] + u.att.part[128+a0+1];
        hd4.z = u.att.part[a0+2] + u.att.part[128+a0+2];
        hd4.w = u.att.part[a0+3] + u.att.part[128+a0+3];
        const u16* epr = P.enc_projb + ((size_t)(b*TENC + t0))*AN + a0;
        #pragma unroll
        for (int i = 0; i < 8; i++){
            int p = pg*8 + i;
            if (p < nv){
                float4 er = ld_bf4(epr + (size_t)p*AN);
                float x0 = er.x + hd4.x, x1 = er.y + hd4.y;
                float x2 = er.z + hd4.z, x3 = er.w + hd4.w;
                #pragma unroll
                for (int f = 0; f < NFC; f++){
                    float lf = u.att.loc[p][f];
                    x0 += lf*wl[f].x; x1 += lf*wl[f].y;
                    x2 += lf*wl[f].z; x3 += lf*wl[f].w;
                }
                u.att.ep[p][ag] = vv.x*ftanh(x0) + vv.y*ftanh(x1)
                                + vv.z*ftanh(x2) + vv.w*ftanh(x3);
            }
        }
    }
    __syncthreads();
    // ph3: exp + e + S
    if (tid < 64){
        int p = tid;
        float e = 0.f;
        if (p < nv){
            float s0 = 0.f, s1 = 0.f;
            #pragma unroll
            for (int j2 = 0; j2 < 32; j2 += 2){ s0 += u.att.ep[p][j2]; s1 += u.att.ep[p][j2+1]; }
            e = __expf(s0 + s1);   // |energy| <= sum|v| ~ 5.2
        }
        u.att.evals[p] = e;
        e_row[p] = e;
        float se = e;
        #pragma unroll
        for (int off = 32; off; off >>= 1) se += __shfl_xor(se, off);
        if (tid == 0) atomicAdd(SU_w + b, se);
    }
    __syncthreads();
    // ph4: unnormalized ctx partial
    {
        const int dq = tid & 63, pq = tid >> 6;
        const u16* encb = P.encb + ((size_t)(b*TENC + t0))*DENC + dq*4;
        float ax=0.f, ay=0.f, az=0.f, aw=0.f;
        for (int i = 0; i < 16; i++){
            int p = pq + i*4;
            if (p < nv){
                float ev = u.att.evals[p];
                float4 ex = ld_bf4(encb + (size_t)p*DENC);
                ax += ev*ex.x; ay += ev*ex.y; az += ev*ex.z; aw += ev*ex.w;
            }
        }
        float4 r; r.x=ax; r.y=ay; r.z=az; r.w=aw;
        *(float4*)&u.att.wacc[pq][dq*4] = r;
    }
    __syncthreads();
    // ph5: reduce + global accumulate
    {
        float s = u.att.wacc[0][tid] + u.att.wacc[1][tid]
                + u.att.wacc[2][tid] + u.att.wacc[3][tid];
        atomicAdd(ctxU_w + b*DENC + tid, s);
    }
}

extern "C" void kernel_launch(void* const* d_in, const int* in_sizes, int n_in,
                              void* d_out, int out_size, void* d_ws, size_t ws_size,
                              hipStream_t stream)
{
    const float* enc     = (const float*)d_in[0];
    const int*   lengths = (const int*)  d_in[1];
    const int*   targets = (const int*)  d_in[2];
    const float* emb     = (const float*)d_in[3];
    const float* W_ih    = (const float*)d_in[4];
    const float* W_hh    = (const float*)d_in[5];
    const float* b_ih    = (const float*)d_in[6];
    const float* b_hh    = (const float*)d_in[7];
    const float* conv_w  = (const float*)d_in[8];
    const float* W_enc   = (const float*)d_in[9];
    const float* W_dec   = (const float*)d_in[10];
    const float* W_loc   = (const float*)d_in[11];
    const float* v_w     = (const float*)d_in[12];
    const float* out_w1  = (const float*)d_in[13];
    const float* out_b1  = (const float*)d_in[14];
    const float* out_w2  = (const float*)d_in[15];
    const float* out_b2  = (const float*)d_in[16];
    float* out = (float*)d_out;

    float* ws = (float*)d_ws;
    size_t off = 0;
    auto alloc = [&](size_t n){ float* p = ws + off; off += n; return p; };
    u16*   encb      = (u16*)  alloc((size_t)BB*TENC*DENC/2);
    u16*   enc_projb = (u16*)  alloc((size_t)BB*TENC*AN/2);
    u16*   WdecTb    = (u16*)  alloc(256*128/2);
    float* WcombP    = alloc(576*1024);
    float* biasw     = alloc(1024);
    float* W1T       = alloc(512*256);
    float* W2T       = alloc(256*96);
    float* e0        = alloc(BB*TENC);
    float* e1        = alloc(BB*TENC);
    float* ctxU0     = alloc(BB*DENC);
    float* ctxU1     = alloc(BB*DENC);
    float* SU0       = alloc(BB);
    float* SU1       = alloc(BB);
    float* h0        = alloc(BB*HN);
    float* h1        = alloc(BB*HN);
    float* c_st      = alloc(BB*HN);
    float* hidA      = alloc(BB*HN);
    float* hidB      = alloc(BB*HN);
    u16*   locb      = (u16*)  alloc((size_t)BB*TENC*NFC/2);
    if (off * sizeof(float) > ws_size) return;   // visible failure if ws too small

    Params pr;
    pr.encb = encb; pr.enc_projb = enc_projb; pr.WdecTb = WdecTb;
    pr.conv_w = conv_w; pr.W_loc = W_loc; pr.v_w = v_w;
    pr.lengths = lengths; pr.targets = targets; pr.emb = emb;
    pr.WcombP = WcombP; pr.biasw = biasw;
    pr.W1T = W1T; pr.out_b1 = out_b1; pr.W2T = W2T; pr.out_b2 = out_b2;
    pr.e0 = e0; pr.e1 = e1; pr.ctxU0 = ctxU0; pr.ctxU1 = ctxU1;
    pr.SU0 = SU0; pr.SU1 = SU1; pr.h0 = h0; pr.h1 = h1;
    pr.c_st = c_st; pr.hidA = hidA; pr.hidB = hidB;
    pr.locb = locb; pr.out = out;

    k_prep<<<dim3(512), dim3(256), 0, stream>>>(pr, enc, W_ih, W_hh, b_ih, b_hh, W_dec,
                                                out_w1, out_w2);
    k_encproj<<<dim3(2048), dim3(128), 0, stream>>>(enc, W_enc, enc_projb);

    for (int t = 0; t <= 256; t++){
        k_cell<<<dim3(576), dim3(256), 0, stream>>>(pr, t);
        if (t <= 254)
            k_att<<<dim3(1024), dim3(256), 0, stream>>>(pr, t);
    }
}